// Round 4
// baseline (36.332 us; speedup 1.0000x reference)
//
#include <hip/hip_runtime.h>

// Problem constants from the reference (B=4, N=1024, D=256).
#define B_DIM 4
#define N_DIM 1024
#define D_DIM 256   // ej < 256 always (nonzero over last dim of x)
#define NROWS (B_DIM * N_DIM)   // 4096 (b,i) rows
#define ITILE 16                // i-rows per block
#define LDPAD 4                 // d_lds row stride 260 floats (2-way banks in epilogue)

typedef __bf16 bf16x8 __attribute__((ext_vector_type(8)));
typedef float  f32x4  __attribute__((ext_vector_type(4)));

// ---- Kernel 1: row_start[r] = first edge e with eb[e]*N + ei[e] >= r ------
// Edges from jnp.nonzero are sorted row-major, so keys are nondecreasing.
__global__ __launch_bounds__(256) void row_start_kernel(
    const int* __restrict__ eb, const int* __restrict__ ei,
    int* __restrict__ row_start, int E)
{
    const int r = blockIdx.x * 256 + (int)threadIdx.x;
    if (r > NROWS) return;
    int lo = 0, hi = E;
    while (lo < hi) {
        const int mid = (lo + hi) >> 1;
        const int key = eb[mid] * N_DIM + ei[mid];
        if (key < r) lo = mid + 1; else hi = mid;
    }
    row_start[r] = lo;
}

// ---- Kernel 2: fused Gram-distance tile + edge scatter --------------------
// Block = 256 threads (4 waves). Block handles 16 i-rows x all 256 j.
// Wave w computes the 16x64 sub-tile j in [w*64, w*64+64) via 4 MFMA frags.
// d^2 = n_i + n_j - 2<x_i,x_j> (bf16 Gram, f32 norms), diag forced to 0.
// Then the block scatters its contiguous edge range [row_start[r0],
// row_start[r0+16]) straight to out (32 B per edge, coalesced).
__global__ __launch_bounds__(256) void fused_dist_scatter_kernel(
    const float* __restrict__ x,
    const int* __restrict__ ei, const int* __restrict__ ej,
    const int* __restrict__ row_start,
    float* __restrict__ out)
{
    const int bid = (int)blockIdx.x;          // 0..255
    const int b   = bid >> 6;                 // 4 batches
    const int i0  = (bid & 63) * ITILE;       // 64 i-tiles per batch
    const float* __restrict__ Xb = x + (size_t)b * N_DIM * D_DIM;

    __shared__ float d_lds[ITILE][D_DIM + LDPAD];

    const int lane = (int)(threadIdx.x & 63u);
    const int wid  = (int)(threadIdx.x >> 6);
    const int jbase = wid * 64;

    const int rsel = lane & 15;    // fragment row/col select
    const int kg   = lane >> 4;    // k-group 0..3

    f32x4 acc[4] = {};
    float na = 0.f;                // partial ||x_{i0+rsel}||^2
    float nb[4] = {0.f, 0.f, 0.f, 0.f};

    for (int k0 = 0; k0 < D_DIM; k0 += 32) {
        bf16x8 af;
        {
            const float* rp = Xb + (size_t)(i0 + rsel) * D_DIM + k0 + kg * 8;
            float4 v0 = *(const float4*)rp;
            float4 v1 = *(const float4*)(rp + 4);
            af[0]=(__bf16)v0.x; af[1]=(__bf16)v0.y; af[2]=(__bf16)v0.z; af[3]=(__bf16)v0.w;
            af[4]=(__bf16)v1.x; af[5]=(__bf16)v1.y; af[6]=(__bf16)v1.z; af[7]=(__bf16)v1.w;
            na += v0.x*v0.x + v0.y*v0.y + v0.z*v0.z + v0.w*v0.w
                + v1.x*v1.x + v1.y*v1.y + v1.z*v1.z + v1.w*v1.w;
        }
        bf16x8 bfrag[4];
        #pragma unroll
        for (int f = 0; f < 4; ++f) {
            const float* rp = Xb + (size_t)(jbase + f * 16 + rsel) * D_DIM + k0 + kg * 8;
            float4 v0 = *(const float4*)rp;
            float4 v1 = *(const float4*)(rp + 4);
            bfrag[f][0]=(__bf16)v0.x; bfrag[f][1]=(__bf16)v0.y; bfrag[f][2]=(__bf16)v0.z; bfrag[f][3]=(__bf16)v0.w;
            bfrag[f][4]=(__bf16)v1.x; bfrag[f][5]=(__bf16)v1.y; bfrag[f][6]=(__bf16)v1.z; bfrag[f][7]=(__bf16)v1.w;
            nb[f] += v0.x*v0.x + v0.y*v0.y + v0.z*v0.z + v0.w*v0.w
                   + v1.x*v1.x + v1.y*v1.y + v1.z*v1.z + v1.w*v1.w;
        }
        #pragma unroll
        for (int f = 0; f < 4; ++f)
            acc[f] = __builtin_amdgcn_mfma_f32_16x16x32_bf16(af, bfrag[f], acc[f], 0, 0, 0);
    }

    // Reduce partial norms over the 4 k-groups (lanes sharing lane&15).
    na += __shfl_xor(na, 16, 64);
    na += __shfl_xor(na, 32, 64);
    #pragma unroll
    for (int f = 0; f < 4; ++f) {
        nb[f] += __shfl_xor(nb[f], 16, 64);
        nb[f] += __shfl_xor(nb[f], 32, 64);
    }

    // Epilogue: C/D layout col=lane&15, row=(lane>>4)*4+r (m89-verified).
    #pragma unroll
    for (int f = 0; f < 4; ++f) {
        const int col = jbase + f * 16 + rsel;    // j in [0,256)
        const float nj = nb[f];
        #pragma unroll
        for (int r = 0; r < 4; ++r) {
            const int rloc = kg * 4 + r;          // i-row within tile
            const float ni = __shfl(na, rloc, 64);
            float d2 = ni + nj - 2.0f * acc[f][r];
            float d  = sqrtf(fmaxf(d2, 0.0f));
            if (i0 + rloc == col) d = 0.0f;       // exact zero on diagonal
            d_lds[rloc][col] = d;
        }
    }
    __syncthreads();

    // Scatter phase: this block's contiguous edge range.
    const int r0     = b * N_DIM + i0;
    const int estart = row_start[r0];
    const int eend   = row_start[r0 + ITILE];
    for (int e = estart + (int)threadIdx.x; e < eend; e += 256) {
        const int iloc = ei[e] - i0;
        const int j    = ej[e];
        const float d  = d_lds[iloc][j];
        const float4 v = make_float4(d, d, d, d);
        float* op = out + (size_t)e * 8;
        *(float4*)op       = v;
        *(float4*)(op + 4) = v;
    }
}

// ---- Fallback (ws too small): direct per-edge wave ------------------------
__global__ __launch_bounds__(256) void edge_dist_direct_kernel(
    const float* __restrict__ x,
    const int* __restrict__ eb, const int* __restrict__ ei,
    const int* __restrict__ ej, float* __restrict__ out, int E)
{
    const int wave = (int)((blockIdx.x * (unsigned)blockDim.x + threadIdx.x) >> 6);
    if (wave >= E) return;
    const int lane = (int)(threadIdx.x & 63u);
    const int b = eb[wave], i = ei[wave], j = ej[wave];
    const float4 a = reinterpret_cast<const float4*>(x + ((size_t)b * N_DIM + i) * D_DIM)[lane];
    const float4 c = reinterpret_cast<const float4*>(x + ((size_t)b * N_DIM + j) * D_DIM)[lane];
    const float dx = a.x - c.x, dy = a.y - c.y, dz = a.z - c.z, dw = a.w - c.w;
    float s = dx * dx + dy * dy + dz * dz + dw * dw;
    #pragma unroll
    for (int off = 32; off >= 1; off >>= 1) s += __shfl_xor(s, off, 64);
    const float d = sqrtf(s);
    if (lane < 2)
        reinterpret_cast<float4*>(out + (size_t)wave * 8)[lane] =
            make_float4(d, d, d, d);
}

extern "C" void kernel_launch(void* const* d_in, const int* in_sizes, int n_in,
                              void* d_out, int out_size, void* d_ws, size_t ws_size,
                              hipStream_t stream) {
    const float* x  = (const float*)d_in[0];
    const int*   eb = (const int*)d_in[1];
    const int*   ei = (const int*)d_in[2];
    const int*   ej = (const int*)d_in[3];
    float* out = (float*)d_out;
    const int E = in_sizes[1];
    if (E <= 0) return;

    const size_t rs_bytes = (size_t)(NROWS + 1) * sizeof(int);   // ~16 KB

    if (ws_size >= rs_bytes) {
        int* row_start = (int*)d_ws;
        row_start_kernel<<<(NROWS + 1 + 255) / 256, 256, 0, stream>>>(eb, ei, row_start, E);
        fused_dist_scatter_kernel<<<256, 256, 0, stream>>>(x, ei, ej, row_start, out);
    } else {
        const int blocks = (E + 3) / 4;  // 4 waves/block
        edge_dist_direct_kernel<<<blocks, 256, 0, stream>>>(x, eb, ei, ej, out, E);
    }
}

// Round 5
// 35.013 us; speedup vs baseline: 1.0376x; 1.0376x over previous
//
#include <hip/hip_runtime.h>

// Problem constants from the reference (B=4, N=1024, D=256).
#define B_DIM 4
#define N_DIM 1024
#define D_DIM 256   // ej < 256 always (nonzero over last dim of x)
#define NROWS (B_DIM * N_DIM)   // 4096 (b,i) rows
#define ITILE 16                // i-rows per block
#define LDPAD 4                 // d_lds row stride 260 floats

typedef __bf16 bf16x8 __attribute__((ext_vector_type(8)));
typedef float  f32x4  __attribute__((ext_vector_type(4)));

// ---- Kernel 1: row_start via boundary scatter (no dependent-load chains) --
// Edges from jnp.nonzero are sorted row-major => keys nondecreasing.
// row_start[r] = first e with key[e] >= r. Thread e fills (key[e-1], key[e]].
__global__ __launch_bounds__(256) void row_bounds_kernel(
    const int* __restrict__ eb, const int* __restrict__ ei,
    int* __restrict__ row_start, int E)
{
    const int e = blockIdx.x * 256 + (int)threadIdx.x;
    if (e >= E) return;
    const int key  = eb[e] * N_DIM + ei[e];
    const int prev = (e == 0) ? -1 : (eb[e - 1] * N_DIM + ei[e - 1]);
    for (int r = prev + 1; r <= key; ++r) row_start[r] = e;
    if (e == E - 1) {
        for (int r = key + 1; r <= NROWS; ++r) row_start[r] = E;
    }
}

// ---- Kernel 2: fused Gram-distance tile + edge scatter --------------------
// Block = 512 threads (8 waves, 2 waves/SIMD). Block handles 16 i-rows x 256 j.
// Wave w computes the 16x32 sub-tile j in [w*32, w*32+32) via 2 MFMA frags.
// d^2 = n_i + n_j - 2<x_i,x_j> (bf16 Gram, f32 norms), diag forced to 0.
// Then the block scatters its contiguous edge range straight to out.
__global__ __launch_bounds__(512) void fused_dist_scatter_kernel(
    const float* __restrict__ x,
    const int* __restrict__ ei, const int* __restrict__ ej,
    const int* __restrict__ row_start,
    float* __restrict__ out)
{
    const int bid = (int)blockIdx.x;          // 0..255
    const int b   = bid >> 6;                 // 4 batches
    const int i0  = (bid & 63) * ITILE;       // 64 i-tiles per batch
    const float* __restrict__ Xb = x + (size_t)b * N_DIM * D_DIM;

    __shared__ float d_lds[ITILE][D_DIM + LDPAD];

    const int lane = (int)(threadIdx.x & 63u);
    const int wid  = (int)(threadIdx.x >> 6);  // 0..7
    const int jbase = wid * 32;

    const int rsel = lane & 15;    // fragment row/col select
    const int kg   = lane >> 4;    // k-group 0..3

    f32x4 acc[2] = {};
    float na = 0.f;                // partial ||x_{i0+rsel}||^2
    float nb[2] = {0.f, 0.f};

    for (int k0 = 0; k0 < D_DIM; k0 += 32) {
        bf16x8 af;
        {
            const float* rp = Xb + (size_t)(i0 + rsel) * D_DIM + k0 + kg * 8;
            float4 v0 = *(const float4*)rp;
            float4 v1 = *(const float4*)(rp + 4);
            af[0]=(__bf16)v0.x; af[1]=(__bf16)v0.y; af[2]=(__bf16)v0.z; af[3]=(__bf16)v0.w;
            af[4]=(__bf16)v1.x; af[5]=(__bf16)v1.y; af[6]=(__bf16)v1.z; af[7]=(__bf16)v1.w;
            na += v0.x*v0.x + v0.y*v0.y + v0.z*v0.z + v0.w*v0.w
                + v1.x*v1.x + v1.y*v1.y + v1.z*v1.z + v1.w*v1.w;
        }
        bf16x8 bfrag[2];
        #pragma unroll
        for (int f = 0; f < 2; ++f) {
            const float* rp = Xb + (size_t)(jbase + f * 16 + rsel) * D_DIM + k0 + kg * 8;
            float4 v0 = *(const float4*)rp;
            float4 v1 = *(const float4*)(rp + 4);
            bfrag[f][0]=(__bf16)v0.x; bfrag[f][1]=(__bf16)v0.y; bfrag[f][2]=(__bf16)v0.z; bfrag[f][3]=(__bf16)v0.w;
            bfrag[f][4]=(__bf16)v1.x; bfrag[f][5]=(__bf16)v1.y; bfrag[f][6]=(__bf16)v1.z; bfrag[f][7]=(__bf16)v1.w;
            nb[f] += v0.x*v0.x + v0.y*v0.y + v0.z*v0.z + v0.w*v0.w
                   + v1.x*v1.x + v1.y*v1.y + v1.z*v1.z + v1.w*v1.w;
        }
        #pragma unroll
        for (int f = 0; f < 2; ++f)
            acc[f] = __builtin_amdgcn_mfma_f32_16x16x32_bf16(af, bfrag[f], acc[f], 0, 0, 0);
    }

    // Reduce partial norms over the 4 k-groups (lanes sharing lane&15).
    na += __shfl_xor(na, 16, 64);
    na += __shfl_xor(na, 32, 64);
    #pragma unroll
    for (int f = 0; f < 2; ++f) {
        nb[f] += __shfl_xor(nb[f], 16, 64);
        nb[f] += __shfl_xor(nb[f], 32, 64);
    }

    // Epilogue: C/D layout col=lane&15, row=(lane>>4)*4+r (m89-verified).
    #pragma unroll
    for (int f = 0; f < 2; ++f) {
        const int col = jbase + f * 16 + rsel;    // j in [0,256)
        const float nj = nb[f];
        #pragma unroll
        for (int r = 0; r < 4; ++r) {
            const int rloc = kg * 4 + r;          // i-row within tile
            const float ni = __shfl(na, rloc, 64);
            float d2 = ni + nj - 2.0f * acc[f][r];
            float d  = sqrtf(fmaxf(d2, 0.0f));
            if (i0 + rloc == col) d = 0.0f;       // exact zero on diagonal
            d_lds[rloc][col] = d;
        }
    }
    __syncthreads();

    // Scatter phase: this block's contiguous edge range (coalesced 32 B/edge).
    const int r0     = b * N_DIM + i0;
    const int estart = row_start[r0];
    const int eend   = row_start[r0 + ITILE];
    for (int e = estart + (int)threadIdx.x; e < eend; e += 512) {
        const int iloc = ei[e] - i0;
        const int j    = ej[e];
        const float d  = d_lds[iloc][j];
        const float4 v = make_float4(d, d, d, d);
        float* op = out + (size_t)e * 8;
        *(float4*)op       = v;
        *(float4*)(op + 4) = v;
    }
}

// ---- Fallback (ws too small): direct per-edge wave ------------------------
__global__ __launch_bounds__(256) void edge_dist_direct_kernel(
    const float* __restrict__ x,
    const int* __restrict__ eb, const int* __restrict__ ei,
    const int* __restrict__ ej, float* __restrict__ out, int E)
{
    const int wave = (int)((blockIdx.x * (unsigned)blockDim.x + threadIdx.x) >> 6);
    if (wave >= E) return;
    const int lane = (int)(threadIdx.x & 63u);
    const int b = eb[wave], i = ei[wave], j = ej[wave];
    const float4 a = reinterpret_cast<const float4*>(x + ((size_t)b * N_DIM + i) * D_DIM)[lane];
    const float4 c = reinterpret_cast<const float4*>(x + ((size_t)b * N_DIM + j) * D_DIM)[lane];
    const float dx = a.x - c.x, dy = a.y - c.y, dz = a.z - c.z, dw = a.w - c.w;
    float s = dx * dx + dy * dy + dz * dz + dw * dw;
    #pragma unroll
    for (int off = 32; off >= 1; off >>= 1) s += __shfl_xor(s, off, 64);
    const float d = sqrtf(s);
    if (lane < 2)
        reinterpret_cast<float4*>(out + (size_t)wave * 8)[lane] =
            make_float4(d, d, d, d);
}

extern "C" void kernel_launch(void* const* d_in, const int* in_sizes, int n_in,
                              void* d_out, int out_size, void* d_ws, size_t ws_size,
                              hipStream_t stream) {
    const float* x  = (const float*)d_in[0];
    const int*   eb = (const int*)d_in[1];
    const int*   ei = (const int*)d_in[2];
    const int*   ej = (const int*)d_in[3];
    float* out = (float*)d_out;
    const int E = in_sizes[1];
    if (E <= 0) return;

    const size_t rs_bytes = (size_t)(NROWS + 1) * sizeof(int);   // ~16 KB

    if (ws_size >= rs_bytes) {
        int* row_start = (int*)d_ws;
        row_bounds_kernel<<<(E + 255) / 256, 256, 0, stream>>>(eb, ei, row_start, E);
        fused_dist_scatter_kernel<<<256, 512, 0, stream>>>(x, ei, ej, row_start, out);
    } else {
        const int blocks = (E + 3) / 4;  // 4 waves/block
        edge_dist_direct_kernel<<<blocks, 256, 0, stream>>>(x, eb, ei, ej, out, E);
    }
}